// Round 1
// baseline (401.692 us; speedup 1.0000x reference)
//
#include <hip/hip_runtime.h>

#define NWIN 49
#define DIM  128
#define NH   4
#define HD   32
#define SCALE 0.17677669529663687f

using short8 = __attribute__((ext_vector_type(8))) short;
using us4    = __attribute__((ext_vector_type(4))) unsigned short;
using f32x4  = __attribute__((ext_vector_type(4))) float;

union Frag { uint4 u; short8 s; };

static __device__ __forceinline__ short8 ld8(const unsigned short* p) {
    Frag fr; fr.u = *(const uint4*)p; return fr.s;
}
static __device__ __forceinline__ unsigned short f2bf(float f) {
    union { float f; unsigned i; } v; v.f = f;
    unsigned r = v.i + 0x7fffu + ((v.i >> 16) & 1u);   // RNE
    return (unsigned short)(r >> 16);
}

// ---- prep: bf16 transposed weights + precombined bias+mask table ----
__global__ __launch_bounds__(256) void prep_kernel(
    const float* __restrict__ qkv_w,    // [128,384]
    const float* __restrict__ proj_w,   // [128,128]
    const float* __restrict__ mask,     // [64,49,49]
    const float* __restrict__ bias_tab, // [169,4]
    const int*   __restrict__ rel_index,// [49,49]
    unsigned short* __restrict__ wqkvT, // [384,128] bf16
    unsigned short* __restrict__ projT, // [128,128] bf16
    float*          __restrict__ BM)    // [64,4,49,49] fp32: mask+bias
{
    int tid = blockIdx.x * 256 + threadIdx.x;
    if (tid < 49152) {
        int n = tid >> 7, k = tid & 127;
        wqkvT[tid] = f2bf(qkv_w[k * 384 + n]);
    } else if (tid < 65536) {
        int t2 = tid - 49152;
        int n = t2 >> 7, k = t2 & 127;
        projT[t2] = f2bf(proj_w[k * 128 + n]);
    } else if (tid < 65536 + 64 * NH * 2401) {
        int idx = tid - 65536;
        int wh = idx / 2401, ij = idx % 2401;
        int wm = wh >> 2, h = wh & 3;
        BM[idx] = mask[wm * 2401 + ij] + bias_tab[rel_index[ij] * NH + h];
    }
}

// ====================================================================
// NEW PATH: split QKV GEMM from attention.
//
// qkv_kernel: per-window 64x384x128 bf16 GEMM (rows 49..63 spill into
//   next window's X, clamped at the global end -> always finite).
//   Outputs:
//     Qb [cw*49+64][128] bf16, col = h*32+d, SCALE folded in
//     Kb [cw*49+64][128] bf16
//     VT [cw][4][32][64]  bf16  (V transposed per head; all 64 k-cols
//                                written finite so pad cols are safe)
//   These layouts make the attention MFMA fragments direct 16B global
//   loads (lane reads 8 consecutive bf16 along the contraction dim).
// ====================================================================
__global__ __launch_bounds__(256) void qkv_kernel(
    const float* __restrict__ x,
    const float* __restrict__ qkv_b,
    const unsigned short* __restrict__ wqkvT,
    unsigned short* __restrict__ Qb,
    unsigned short* __restrict__ Kb,
    unsigned short* __restrict__ VT,
    int c0, int Mtot)
{
    __shared__ __align__(16) unsigned short XS[64 * 136];
    const int lb = blockIdx.x, t = threadIdx.x;
    const int w = t >> 6, lane = t & 63, q = lane >> 4, l16 = lane & 15;

    // stage X rows [0,64) of this window (spill rows clamped -> finite)
    for (int c = t; c < 64 * 16; c += 256) {
        const int row = c >> 4, g = c & 15;
        int grow = (c0 + lb) * NWIN + row;
        if (grow > Mtot - 1) grow = Mtot - 1;
        const float4* src = (const float4*)(x + (size_t)grow * DIM + g * 8);
        float4 f0 = src[0], f1 = src[1];
        uint4 p;
        p.x = (unsigned)f2bf(f0.x) | ((unsigned)f2bf(f0.y) << 16);
        p.y = (unsigned)f2bf(f0.z) | ((unsigned)f2bf(f0.w) << 16);
        p.z = (unsigned)f2bf(f1.x) | ((unsigned)f2bf(f1.y) << 16);
        p.w = (unsigned)f2bf(f1.z) | ((unsigned)f2bf(f1.w) << 16);
        *(uint4*)(XS + row * 136 + g * 8) = p;
    }
    __syncthreads();

    // hoist all A-fragments once (16 x ld8 = 64 VGPR)
    short8 af[4][4];
    #pragma unroll
    for (int mt = 0; mt < 4; ++mt)
        #pragma unroll
        for (int ks = 0; ks < 4; ++ks)
            af[mt][ks] = ld8(XS + (mt * 16 + l16) * 136 + ks * 32 + q * 8);

    // wave w handles cols {s*128 + w*32 + nn*16} for s in {q,k,v}
    #pragma unroll
    for (int sn = 0; sn < 6; ++sn) {
        const int s = sn >> 1, nn = sn & 1;
        const int colbase = s * 128 + w * 32 + nn * 16;
        short8 bfr[4];
        #pragma unroll
        for (int ks = 0; ks < 4; ++ks)
            bfr[ks] = ld8(wqkvT + (size_t)(colbase + l16) * 128 + ks * 32 + q * 8);
        const float bias = qkv_b[colbase + l16];
        const int cl = nn * 16 + l16;
        #pragma unroll
        for (int mt = 0; mt < 4; ++mt) {
            f32x4 acc = {0.f, 0.f, 0.f, 0.f};
            #pragma unroll
            for (int ks = 0; ks < 4; ++ks)
                acc = __builtin_amdgcn_mfma_f32_16x16x32_bf16(af[mt][ks], bfr[ks], acc, 0, 0, 0);
            if (s == 2) {
                // V^T: lane's 4 acc values are 4 consecutive window rows -> one 8B store
                us4 pk;
                #pragma unroll
                for (int r = 0; r < 4; ++r) pk[r] = f2bf(acc[r] + bias);
                *(us4*)(VT + ((size_t)(lb * 4 + w) * 32 + cl) * 64 + mt * 16 + q * 4) = pk;
            } else {
                #pragma unroll
                for (int r = 0; r < 4; ++r) {
                    const int row = mt * 16 + q * 4 + r;
                    if (row < NWIN) {
                        const float val = acc[r] + bias;
                        if (s == 0)
                            Qb[(size_t)(lb * NWIN + row) * 128 + w * 32 + cl] = f2bf(val * SCALE);
                        else
                            Kb[(size_t)(lb * NWIN + row) * 128 + w * 32 + cl] = f2bf(val);
                    }
                }
            }
        }
    }
}

// LDS: OS [49][136] us (13328 B) + per-wave PS [64][72] us (9216 B x 4)
//  = 50192 B -> 3 blocks/CU (vs 2 for the fused kernel).
#define PSS 72
#define OSS 136
#define OS_BYTES  (NWIN * OSS * 2)
#define PSW_BYTES (64 * PSS * 2)

__global__ __launch_bounds__(256) void attn_kernel(
    const unsigned short* __restrict__ Qb,
    const unsigned short* __restrict__ Kb,
    const unsigned short* __restrict__ VT,
    const float* __restrict__ BM,       // [64,4,49,49]
    const unsigned short* __restrict__ projT,  // [128,128] bf16
    const float* __restrict__ proj_b,
    float* __restrict__ out,            // chunk base
    int c0)
{
    __shared__ __align__(16) char pool[OS_BYTES + 4 * PSW_BYTES];
    unsigned short* OS = (unsigned short*)pool;

    const int lb = blockIdx.x, t = threadIdx.x;
    const int w = t >> 6, lane = t & 63, q = lane >> 4, l16 = lane & 15;
    const int h = w, wm = (c0 + lb) & 63;
    unsigned short* PS = (unsigned short*)(pool + OS_BYTES + w * PSW_BYTES);

    const unsigned short* qb = Qb + (size_t)lb * NWIN * 128 + h * 32 + q * 8;
    const unsigned short* kb = Kb + (size_t)lb * NWIN * 128 + h * 32 + q * 8;

    // ---- S = Q K^T : fragments straight from global ----
    float sv[4][4][4];  // [mt][nt][r]
    {
        short8 kf[4];
        #pragma unroll
        for (int nt = 0; nt < 4; ++nt)
            kf[nt] = ld8(kb + (nt * 16 + l16) * 128);
        #pragma unroll
        for (int mt = 0; mt < 4; ++mt) {
            short8 a = ld8(qb + (mt * 16 + l16) * 128);
            #pragma unroll
            for (int nt = 0; nt < 4; ++nt) {
                f32x4 acc = {0.f, 0.f, 0.f, 0.f};
                acc = __builtin_amdgcn_mfma_f32_16x16x32_bf16(a, kf[nt], acc, 0, 0, 0);
                #pragma unroll
                for (int r = 0; r < 4; ++r) sv[mt][nt][r] = acc[r];
            }
        }
    }
    // ---- add combined bias+mask; pad cols -> -inf ----
    {
        const float* bm = BM + (size_t)(wm * NH + h) * 2401;
        #pragma unroll
        for (int mt = 0; mt < 4; ++mt)
            #pragma unroll
            for (int r = 0; r < 4; ++r) {
                const int i = mt * 16 + q * 4 + r;
                const float* bmr = bm + i * 49;
                #pragma unroll
                for (int nt = 0; nt < 4; ++nt) {
                    const int j = nt * 16 + l16;
                    if (j >= NWIN)      sv[mt][nt][r] = -1e30f;   // overwrite: NaN-safe
                    else if (i < NWIN)  sv[mt][nt][r] += bmr[j];
                }
            }
    }
    // ---- softmax per row, 1/sum folded into P; P -> LDS ----
    #pragma unroll
    for (int mt = 0; mt < 4; ++mt)
        #pragma unroll
        for (int r = 0; r < 4; ++r) {
            float m = fmaxf(fmaxf(sv[mt][0][r], sv[mt][1][r]),
                            fmaxf(sv[mt][2][r], sv[mt][3][r]));
            m = fmaxf(m, __shfl_xor(m, 1));
            m = fmaxf(m, __shfl_xor(m, 2));
            m = fmaxf(m, __shfl_xor(m, 4));
            m = fmaxf(m, __shfl_xor(m, 8));
            float sum = 0.f;
            #pragma unroll
            for (int nt = 0; nt < 4; ++nt) {
                float e = __expf(sv[mt][nt][r] - m);
                sv[mt][nt][r] = e;
                sum += e;
            }
            sum += __shfl_xor(sum, 1);
            sum += __shfl_xor(sum, 2);
            sum += __shfl_xor(sum, 4);
            sum += __shfl_xor(sum, 8);
            const float rs = 1.f / sum;
            const int i = mt * 16 + q * 4 + r;
            if (i < NWIN) {
                #pragma unroll
                for (int nt = 0; nt < 4; ++nt)
                    PS[i * PSS + nt * 16 + l16] = f2bf(sv[mt][nt][r] * rs);
            }
        }

    // ---- O_h = P V (V^T fragments straight from global) ----
    const unsigned short* vb = VT + (size_t)(lb * 4 + h) * 32 * 64;
    #pragma unroll
    for (int nt2 = 0; nt2 < 2; ++nt2) {
        short8 bv0 = ld8(vb + (nt2 * 16 + l16) * 64 + q * 8);
        short8 bv1 = ld8(vb + (nt2 * 16 + l16) * 64 + 32 + q * 8);
        #pragma unroll
        for (int mt = 0; mt < 4; ++mt) {
            f32x4 acc = {0.f, 0.f, 0.f, 0.f};
            acc = __builtin_amdgcn_mfma_f32_16x16x32_bf16(
                ld8(PS + (mt * 16 + l16) * PSS + q * 8), bv0, acc, 0, 0, 0);
            acc = __builtin_amdgcn_mfma_f32_16x16x32_bf16(
                ld8(PS + (mt * 16 + l16) * PSS + 32 + q * 8), bv1, acc, 0, 0, 0);
            #pragma unroll
            for (int r = 0; r < 4; ++r) {
                const int row = mt * 16 + q * 4 + r;
                if (row < NWIN)
                    OS[row * OSS + h * 32 + nt2 * 16 + l16] = f2bf(acc[r]);
            }
        }
    }
    __syncthreads();   // the ONLY barrier: full O assembled

    // ---- out = O @ proj_w + proj_b ----
    for (int job = w; job < 32; job += 4) {
        const int mt = job >> 3, nt = job & 7;
        f32x4 acc = {0.f, 0.f, 0.f, 0.f};
        const unsigned short* arow = OS + (mt * 16 + l16) * OSS + q * 8;
        const unsigned short* brow = projT + (size_t)(nt * 16 + l16) * 128 + q * 8;
        #pragma unroll
        for (int ks = 0; ks < 4; ++ks)
            acc = __builtin_amdgcn_mfma_f32_16x16x32_bf16(ld8(arow + ks * 32),
                                                          ld8(brow + ks * 32), acc, 0, 0, 0);
        const int col = nt * 16 + l16;
        const float pb = proj_b[col];
        #pragma unroll
        for (int r = 0; r < 4; ++r) {
            const int row = mt * 16 + q * 4 + r;
            if (row < NWIN)
                out[(size_t)lb * (NWIN * DIM) + row * 128 + col] = acc[r] + pb;
        }
    }
}

// ====================================================================
// FALLBACK: original fused kernel (used only if workspace is too small
// for the split path).
// ====================================================================
#define XS_STRIDE 136
#define WPOOL_OFF 13328
#define WPOOL_SZ  12448
#define QH_OFF    4608
#define KH_OFF    8528
#define PS_OFF    4608
#define POOL_SZ   65168

__global__ __launch_bounds__(256) void winattn_kernel(
    const float* __restrict__ x,
    const float* __restrict__ qkv_b,
    const float* __restrict__ proj_b,
    const unsigned short* __restrict__ wqkvT,
    const unsigned short* __restrict__ projT,
    const float* __restrict__ BM,
    float*       __restrict__ out)
{
    __shared__ __align__(16) char pool[POOL_SZ];
    unsigned short* XS = (unsigned short*)pool;

    const int b = blockIdx.x;
    const int t = threadIdx.x;
    const int w = t >> 6;
    const int lane = t & 63;
    const int q = lane >> 4;
    const int l16 = lane & 15;
    const int wm = b & 63;
    const int h = w;

    char* wp = pool + WPOOL_OFF + w * WPOOL_SZ;
    unsigned short* VT = (unsigned short*)wp;
    unsigned short* QH = (unsigned short*)(wp + QH_OFF);
    unsigned short* KH = (unsigned short*)(wp + KH_OFF);
    unsigned short* PS = (unsigned short*)(wp + PS_OFF);

    for (int c = t; c < NWIN * 16; c += 256) {
        const int row = c >> 4, g = c & 15;
        const float4* src = (const float4*)(x + (size_t)b * (NWIN * DIM) + row * DIM + g * 8);
        float4 f0 = src[0], f1 = src[1];
        uint4 p;
        p.x = (unsigned)f2bf(f0.x) | ((unsigned)f2bf(f0.y) << 16);
        p.y = (unsigned)f2bf(f0.z) | ((unsigned)f2bf(f0.w) << 16);
        p.z = (unsigned)f2bf(f1.x) | ((unsigned)f2bf(f1.y) << 16);
        p.w = (unsigned)f2bf(f1.z) | ((unsigned)f2bf(f1.w) << 16);
        *(uint4*)(XS + row * XS_STRIDE + g * 8) = p;
    }
    __syncthreads();

    #pragma unroll
    for (int job = 0; job < 24; ++job) {
        const int mt = job & 3, sn = job >> 2, s = sn >> 1, nn = sn & 1;
        const int colbase = s * 128 + h * 32 + nn * 16;
        f32x4 acc = {0.f, 0.f, 0.f, 0.f};
        const unsigned short* arow = XS + (mt * 16 + l16) * XS_STRIDE + q * 8;
        const unsigned short* brow = wqkvT + (size_t)(colbase + l16) * 128 + q * 8;
        #pragma unroll
        for (int ks = 0; ks < 4; ++ks)
            acc = __builtin_amdgcn_mfma_f32_16x16x32_bf16(ld8(arow + ks * 32),
                                                          ld8(brow + ks * 32), acc, 0, 0, 0);
        const float bias = qkv_b[colbase + l16];
        const int cl = nn * 16 + l16;
        #pragma unroll
        for (int r = 0; r < 4; ++r) {
            const int row = mt * 16 + q * 4 + r;
            const float val = acc[r] + bias;
            if (s == 0)      { if (row < NWIN) QH[row * 40 + cl] = f2bf(val * SCALE); }
            else if (s == 1) { if (row < NWIN) KH[row * 40 + cl] = f2bf(val); }
            else             VT[cl * 72 + row] = f2bf(val);
        }
    }
    __syncthreads();

    float sv[4][4][4];
    {
        short8 bfr[4];
        #pragma unroll
        for (int nt = 0; nt < 4; ++nt)
            bfr[nt] = ld8(KH + (nt * 16 + l16) * 40 + q * 8);
        #pragma unroll
        for (int mt = 0; mt < 4; ++mt) {
            short8 a = ld8(QH + (mt * 16 + l16) * 40 + q * 8);
            #pragma unroll
            for (int nt = 0; nt < 4; ++nt) {
                f32x4 acc = {0.f, 0.f, 0.f, 0.f};
                acc = __builtin_amdgcn_mfma_f32_16x16x32_bf16(a, bfr[nt], acc, 0, 0, 0);
                #pragma unroll
                for (int r = 0; r < 4; ++r) sv[mt][nt][r] = acc[r];
            }
        }
    }
    {
        const float* bm = BM + (size_t)(wm * NH + h) * 2401;
        #pragma unroll
        for (int mt = 0; mt < 4; ++mt)
            #pragma unroll
            for (int r = 0; r < 4; ++r) {
                const int i = mt * 16 + q * 4 + r;
                const float* bmr = bm + i * 49;
                #pragma unroll
                for (int nt = 0; nt < 4; ++nt) {
                    const int j = nt * 16 + l16;
                    if (j >= NWIN)      sv[mt][nt][r] = -1e30f;
                    else if (i < NWIN)  sv[mt][nt][r] += bmr[j];
                }
            }
    }
    #pragma unroll
    for (int mt = 0; mt < 4; ++mt)
        #pragma unroll
        for (int r = 0; r < 4; ++r) {
            float m = fmaxf(fmaxf(sv[mt][0][r], sv[mt][1][r]),
                            fmaxf(sv[mt][2][r], sv[mt][3][r]));
            m = fmaxf(m, __shfl_xor(m, 1));
            m = fmaxf(m, __shfl_xor(m, 2));
            m = fmaxf(m, __shfl_xor(m, 4));
            m = fmaxf(m, __shfl_xor(m, 8));
            float sum = 0.f;
            #pragma unroll
            for (int nt = 0; nt < 4; ++nt) {
                float e = __expf(sv[mt][nt][r] - m);
                sv[mt][nt][r] = e;
                sum += e;
            }
            sum += __shfl_xor(sum, 1);
            sum += __shfl_xor(sum, 2);
            sum += __shfl_xor(sum, 4);
            sum += __shfl_xor(sum, 8);
            const float rs = 1.f / sum;
            const int i = mt * 16 + q * 4 + r;
            if (i < NWIN) {
                #pragma unroll
                for (int nt = 0; nt < 4; ++nt)
                    PS[i * 72 + nt * 16 + l16] = f2bf(sv[mt][nt][r] * rs);
            }
        }

    #pragma unroll
    for (int nt2 = 0; nt2 < 2; ++nt2) {
        short8 bv0 = ld8(VT + (nt2 * 16 + l16) * 72 + q * 8);
        short8 bv1 = ld8(VT + (nt2 * 16 + l16) * 72 + 32 + q * 8);
        #pragma unroll
        for (int mt = 0; mt < 4; ++mt) {
            f32x4 acc = {0.f, 0.f, 0.f, 0.f};
            acc = __builtin_amdgcn_mfma_f32_16x16x32_bf16(
                ld8(PS + (mt * 16 + l16) * 72 + q * 8), bv0, acc, 0, 0, 0);
            acc = __builtin_amdgcn_mfma_f32_16x16x32_bf16(
                ld8(PS + (mt * 16 + l16) * 72 + 32 + q * 8), bv1, acc, 0, 0, 0);
            #pragma unroll
            for (int r = 0; r < 4; ++r) {
                const int row = mt * 16 + q * 4 + r;
                if (row < NWIN)
                    XS[row * XS_STRIDE + h * 32 + nt2 * 16 + l16] = f2bf(acc[r]);
            }
        }
    }
    __syncthreads();

    for (int job = w; job < 32; job += 4) {
        const int mt = job >> 3, nt = job & 7;
        f32x4 acc = {0.f, 0.f, 0.f, 0.f};
        const unsigned short* arow = XS + (mt * 16 + l16) * XS_STRIDE + q * 8;
        const unsigned short* brow = projT + (size_t)(nt * 16 + l16) * 128 + q * 8;
        #pragma unroll
        for (int ks = 0; ks < 4; ++ks)
            acc = __builtin_amdgcn_mfma_f32_16x16x32_bf16(ld8(arow + ks * 32),
                                                          ld8(brow + ks * 32), acc, 0, 0, 0);
        const int col = nt * 16 + l16;
        const float pb = proj_b[col];
        #pragma unroll
        for (int r = 0; r < 4; ++r) {
            const int row = mt * 16 + q * 4 + r;
            if (row < NWIN)
                out[(size_t)b * (NWIN * DIM) + row * 128 + col] = acc[r] + pb;
        }
    }
}

extern "C" void kernel_launch(void* const* d_in, const int* in_sizes, int n_in,
                              void* d_out, int out_size, void* d_ws, size_t ws_size,
                              hipStream_t stream) {
    const int B = in_sizes[0] / (NWIN * DIM);  // 4096 windows
    const int M = B * NWIN;
    unsigned short* wqkvT = (unsigned short*)d_ws;                   //    98304 B
    unsigned short* projT = (unsigned short*)((char*)d_ws + 98304);  //    32768 B
    float*          BM    = (float*)((char*)d_ws + 131072);          //  2458624 B
    const size_t FIXED = 131072 + 2458624;                           //  2589696 B

    prep_kernel<<<2657, 256, 0, stream>>>(
        (const float*)d_in[2],  // qkv_w
        (const float*)d_in[4],  // proj_w
        (const float*)d_in[1],  // mask
        (const float*)d_in[6],  // rel_bias_table
        (const int*)d_in[7],    // rel_index
        wqkvT, projT, BM);

    // split-path workspace: per window 41472 B (Q 25088/2-way.. : 2*(49*256)
    // + VT 16384) plus 2*64-row slack (32768 B). Chunk if ws is small.
    size_t CW = 0;
    if (ws_size > FIXED + 32768) {
        size_t avail = ws_size - FIXED;
        CW = (avail - 32768) / 41472;
        if (CW > (size_t)B) CW = (size_t)B;
    }

    if (CW >= 32) {
        char* pbase = (char*)d_ws + FIXED;
        const size_t qk_bytes = ((size_t)CW * NWIN + 64) * 256;  // [rows][128] bf16
        unsigned short* Qb  = (unsigned short*)pbase;
        unsigned short* Kb  = (unsigned short*)(pbase + qk_bytes);
        unsigned short* VTb = (unsigned short*)(pbase + 2 * qk_bytes);
        for (int c0 = 0; c0 < B; c0 += (int)CW) {
            int cw = (B - c0) < (int)CW ? (B - c0) : (int)CW;
            qkv_kernel<<<cw, 256, 0, stream>>>(
                (const float*)d_in[0],  // x
                (const float*)d_in[3],  // qkv_b
                wqkvT, Qb, Kb, VTb, c0, M);
            attn_kernel<<<cw, 256, 0, stream>>>(
                Qb, Kb, VTb, BM, projT,
                (const float*)d_in[5],  // proj_b
                (float*)d_out + (size_t)c0 * NWIN * DIM, c0);
        }
    } else {
        winattn_kernel<<<B, 256, 0, stream>>>(
            (const float*)d_in[0],  // x
            (const float*)d_in[3],  // qkv_b
            (const float*)d_in[5],  // proj_b
            wqkvT, projT, BM,
            (float*)d_out);
    }
}

// Round 2
// 327.449 us; speedup vs baseline: 1.2267x; 1.2267x over previous
//
#include <hip/hip_runtime.h>

#define NWIN 49
#define DIM  128
#define NH   4
#define HD   32
#define SCALE 0.17677669529663687f

using short8 = __attribute__((ext_vector_type(8))) short;
using f32x4  = __attribute__((ext_vector_type(4))) float;

union Frag { uint4 u; short8 s; };

static __device__ __forceinline__ short8 ld8(const unsigned short* p) {
    Frag fr; fr.u = *(const uint4*)p; return fr.s;
}
static __device__ __forceinline__ unsigned short f2bf(float f) {
    union { float f; unsigned i; } v; v.f = f;
    unsigned r = v.i + 0x7fffu + ((v.i >> 16) & 1u);   // RNE
    return (unsigned short)(r >> 16);
}

// ---- prep: bf16 transposed weights + precombined bias+mask table ----
__global__ __launch_bounds__(256) void prep_kernel(
    const float* __restrict__ qkv_w,    // [128,384]
    const float* __restrict__ proj_w,   // [128,128]
    const float* __restrict__ mask,     // [64,49,49]
    const float* __restrict__ bias_tab, // [169,4]
    const int*   __restrict__ rel_index,// [49,49]
    unsigned short* __restrict__ wqkvT, // [384,128] bf16
    unsigned short* __restrict__ projT, // [128,128] bf16
    float*          __restrict__ BM)    // [64,4,49,49] fp32: mask+bias
{
    int tid = blockIdx.x * 256 + threadIdx.x;
    if (tid < 49152) {
        int n = tid >> 7, k = tid & 127;
        wqkvT[tid] = f2bf(qkv_w[k * 384 + n]);
    } else if (tid < 65536) {
        int t2 = tid - 49152;
        int n = t2 >> 7, k = t2 & 127;
        projT[t2] = f2bf(proj_w[k * 128 + n]);
    } else if (tid < 65536 + 64 * NH * 2401) {
        int idx = tid - 65536;
        int wh = idx / 2401, ij = idx % 2401;
        int wm = wh >> 2, h = wh & 3;
        BM[idx] = mask[wm * 2401 + ij] + bias_tab[rel_index[ij] * NH + h];
    }
}

// LDS layout (bytes) — identical to the verified 4-wave kernel:
//  [0, 13328)            XS [49][136] ushort  -- aliased by OS after sync #2
//  [13328 + hp*12448 ...) per-HEAD pool (hp = head 0..3):
//      +0     VT [32][72] ushort (4608)
//      +4608  QH [49][40] ushort (3920)   } aliased by PS [49][72] (7056)
//      +8528  KH [49][40] ushort (3920)   }   after S-tile MFMA reads complete
//  pad to 65168 so spill-reads of pad rows (49..63) stay inside the pool.
#define XS_STRIDE 136
#define WPOOL_OFF 13328
#define WPOOL_SZ  12448
#define QH_OFF    4608
#define KH_OFF    8528
#define PS_OFF    4608
#define POOL_SZ   65168

// 512 threads = 8 waves per window. Same LDS as the 4-wave version ->
// still 2 blocks/CU, but 16 waves/CU (4/SIMD) instead of 8: doubled TLP,
// halved per-wave serial chain (~80 MFMAs vs 160).
__global__ __launch_bounds__(512) void winattn_kernel(
    const float* __restrict__ x,        // [4096,49,128]
    const float* __restrict__ qkv_b,    // [384]
    const float* __restrict__ proj_b,   // [128]
    const unsigned short* __restrict__ wqkvT,  // [384,128] bf16
    const unsigned short* __restrict__ projT,  // [128,128] bf16
    const float* __restrict__ BM,       // [64,4,49,49]
    float*       __restrict__ out)      // [4096,49,128]
{
    __shared__ __align__(16) char pool[POOL_SZ];
    unsigned short* XS = (unsigned short*)pool;   // also OS after sync #2

    const int b = blockIdx.x;
    const int t = threadIdx.x;
    const int w = t >> 6;        // wave 0..7
    const int lane = t & 63;
    const int q = lane >> 4;     // quad 0..3
    const int l16 = lane & 15;
    const int wm = b & 63;

    // ---- stage X -> bf16 LDS [49][136] ----
    for (int c = t; c < NWIN * 16; c += 512) {
        const int row = c >> 4, g = c & 15;
        const float4* src = (const float4*)(x + (size_t)b * (NWIN * DIM) + row * DIM + g * 8);
        float4 f0 = src[0], f1 = src[1];
        uint4 p;
        p.x = (unsigned)f2bf(f0.x) | ((unsigned)f2bf(f0.y) << 16);
        p.y = (unsigned)f2bf(f0.z) | ((unsigned)f2bf(f0.w) << 16);
        p.z = (unsigned)f2bf(f1.x) | ((unsigned)f2bf(f1.y) << 16);
        p.w = (unsigned)f2bf(f1.z) | ((unsigned)f2bf(f1.w) << 16);
        *(uint4*)(XS + row * XS_STRIDE + g * 8) = p;
    }
    __syncthreads();   // sync #1

    // ---- phase B: QKV. Wave w -> head (w&3), mt in {w>>2, (w>>2)+2} ----
    {
        const int hb = w & 3;
        const int mt0 = w >> 2;
        char* wpb = pool + WPOOL_OFF + hb * WPOOL_SZ;
        unsigned short* VTb = (unsigned short*)wpb;
        unsigned short* QHb = (unsigned short*)(wpb + QH_OFF);
        unsigned short* KHb = (unsigned short*)(wpb + KH_OFF);

        short8 af[2][4];
        #pragma unroll
        for (int mti = 0; mti < 2; ++mti) {
            const int mt = mt0 + 2 * mti;
            #pragma unroll
            for (int ks = 0; ks < 4; ++ks)
                af[mti][ks] = ld8(XS + (mt * 16 + l16) * XS_STRIDE + ks * 32 + q * 8);
        }
        #pragma unroll
        for (int sn = 0; sn < 6; ++sn) {
            const int s = sn >> 1, nn = sn & 1;
            const int colbase = s * 128 + hb * 32 + nn * 16;
            short8 bfr[4];
            #pragma unroll
            for (int ks = 0; ks < 4; ++ks)
                bfr[ks] = ld8(wqkvT + (size_t)(colbase + l16) * 128 + ks * 32 + q * 8);
            const float bias = qkv_b[colbase + l16];
            const int cl = nn * 16 + l16;
            #pragma unroll
            for (int mti = 0; mti < 2; ++mti) {
                const int mt = mt0 + 2 * mti;
                f32x4 acc = {0.f, 0.f, 0.f, 0.f};
                #pragma unroll
                for (int ks = 0; ks < 4; ++ks)
                    acc = __builtin_amdgcn_mfma_f32_16x16x32_bf16(af[mti][ks], bfr[ks], acc, 0, 0, 0);
                #pragma unroll
                for (int r = 0; r < 4; ++r) {
                    const int row = mt * 16 + q * 4 + r;
                    const float val = acc[r] + bias;
                    if (s == 0)      { if (row < NWIN) QHb[row * 40 + cl] = f2bf(val * SCALE); }
                    else if (s == 1) { if (row < NWIN) KHb[row * 40 + cl] = f2bf(val); }
                    else             VTb[cl * 72 + row] = f2bf(val);  // row<=63 < 72: in-pad, safe
                }
            }
        }
    }
    __syncthreads();   // sync #2: QKV complete; XS free -> OS may alias it

    // ---- phase C: wave w -> head (w>>1), mt-half (w&1) ----
    const int h = w >> 1, mh = w & 1;
    char* wp = pool + WPOOL_OFF + h * WPOOL_SZ;
    unsigned short* VT = (unsigned short*)wp;
    unsigned short* QH = (unsigned short*)(wp + QH_OFF);
    unsigned short* KH = (unsigned short*)(wp + KH_OFF);
    unsigned short* PS = (unsigned short*)(wp + PS_OFF);

    float sv[2][4][4];  // [mti][nt][r]
    {
        short8 kf[4];
        #pragma unroll
        for (int nt = 0; nt < 4; ++nt)
            kf[nt] = ld8(KH + (nt * 16 + l16) * 40 + q * 8);
        #pragma unroll
        for (int mti = 0; mti < 2; ++mti) {
            const int mt = 2 * mh + mti;
            short8 a = ld8(QH + (mt * 16 + l16) * 40 + q * 8);
            #pragma unroll
            for (int nt = 0; nt < 4; ++nt) {
                f32x4 acc = {0.f, 0.f, 0.f, 0.f};
                acc = __builtin_amdgcn_mfma_f32_16x16x32_bf16(a, kf[nt], acc, 0, 0, 0);
                #pragma unroll
                for (int r = 0; r < 4; ++r) sv[mti][nt][r] = acc[r];
            }
        }
    }
    // add combined bias+mask; pad cols -> -inf  (registers only)
    {
        const float* bm = BM + (size_t)(wm * NH + h) * 2401;
        #pragma unroll
        for (int mti = 0; mti < 2; ++mti)
            #pragma unroll
            for (int r = 0; r < 4; ++r) {
                const int i = (2 * mh + mti) * 16 + q * 4 + r;
                const float* bmr = bm + i * 49;
                #pragma unroll
                for (int nt = 0; nt < 4; ++nt) {
                    const int j = nt * 16 + l16;
                    if (j >= NWIN)      sv[mti][nt][r] = -1e30f;
                    else if (i < NWIN)  sv[mti][nt][r] += bmr[j];
                    // i>=49: garbage, confined to never-stored rows
                }
            }
    }
    // softmax per row, fully in registers (normalized P left in sv)
    #pragma unroll
    for (int mti = 0; mti < 2; ++mti)
        #pragma unroll
        for (int r = 0; r < 4; ++r) {
            float m = fmaxf(fmaxf(sv[mti][0][r], sv[mti][1][r]),
                            fmaxf(sv[mti][2][r], sv[mti][3][r]));
            m = fmaxf(m, __shfl_xor(m, 1));
            m = fmaxf(m, __shfl_xor(m, 2));
            m = fmaxf(m, __shfl_xor(m, 4));
            m = fmaxf(m, __shfl_xor(m, 8));
            float sum = 0.f;
            #pragma unroll
            for (int nt = 0; nt < 4; ++nt) {
                float e = __expf(sv[mti][nt][r] - m);
                sv[mti][nt][r] = e;
                sum += e;
            }
            sum += __shfl_xor(sum, 1);
            sum += __shfl_xor(sum, 2);
            sum += __shfl_xor(sum, 4);
            sum += __shfl_xor(sum, 8);
            const float rs = 1.f / sum;
            #pragma unroll
            for (int nt = 0; nt < 4; ++nt) sv[mti][nt][r] *= rs;
        }

    // The 2 waves sharing this head pool must BOTH finish their S-MFMA
    // reads of QH/KH before PS (which aliases them) is written.
    __syncthreads();   // sync #2b

    // P -> LDS (own 32-row half only)
    #pragma unroll
    for (int mti = 0; mti < 2; ++mti)
        #pragma unroll
        for (int r = 0; r < 4; ++r) {
            const int i = (2 * mh + mti) * 16 + q * 4 + r;
            if (i < NWIN) {
                #pragma unroll
                for (int nt = 0; nt < 4; ++nt)
                    PS[i * 72 + nt * 16 + l16] = f2bf(sv[mti][nt][r]);
            }
        }

    // ---- phase D: O_h = P V (own rows; PS rows are self-written) ----
    #pragma unroll
    for (int nt2 = 0; nt2 < 2; ++nt2) {
        short8 bv0 = ld8(VT + (nt2 * 16 + l16) * 72 + q * 8);
        short8 bv1 = ld8(VT + (nt2 * 16 + l16) * 72 + 32 + q * 8);
        #pragma unroll
        for (int mti = 0; mti < 2; ++mti) {
            const int mt = 2 * mh + mti;
            f32x4 acc = {0.f, 0.f, 0.f, 0.f};
            acc = __builtin_amdgcn_mfma_f32_16x16x32_bf16(
                ld8(PS + (mt * 16 + l16) * 72 + q * 8), bv0, acc, 0, 0, 0);
            acc = __builtin_amdgcn_mfma_f32_16x16x32_bf16(
                ld8(PS + (mt * 16 + l16) * 72 + 32 + q * 8), bv1, acc, 0, 0, 0);
            #pragma unroll
            for (int r = 0; r < 4; ++r) {
                const int row = mt * 16 + q * 4 + r;
                if (row < NWIN)
                    XS[row * XS_STRIDE + h * 32 + nt2 * 16 + l16] = f2bf(acc[r]);  // OS
            }
        }
    }
    __syncthreads();   // sync #3: full O assembled

    // ---- phase E: out = O @ proj_w + proj_b. Wave w -> col-tile nt=w ----
    {
        const int nt = w;
        short8 bfr[4];
        #pragma unroll
        for (int ks = 0; ks < 4; ++ks)
            bfr[ks] = ld8(projT + (size_t)(nt * 16 + l16) * 128 + ks * 32 + q * 8);
        const int col = nt * 16 + l16;
        const float pb = proj_b[col];
        #pragma unroll
        for (int mt = 0; mt < 4; ++mt) {
            f32x4 acc = {0.f, 0.f, 0.f, 0.f};
            const unsigned short* arow = XS + (mt * 16 + l16) * XS_STRIDE + q * 8;
            #pragma unroll
            for (int ks = 0; ks < 4; ++ks)
                acc = __builtin_amdgcn_mfma_f32_16x16x32_bf16(ld8(arow + ks * 32),
                                                              bfr[ks], acc, 0, 0, 0);
            #pragma unroll
            for (int r = 0; r < 4; ++r) {
                const int row = mt * 16 + q * 4 + r;
                if (row < NWIN)
                    out[(size_t)b * (NWIN * DIM) + row * 128 + col] = acc[r] + pb;
            }
        }
    }
}

extern "C" void kernel_launch(void* const* d_in, const int* in_sizes, int n_in,
                              void* d_out, int out_size, void* d_ws, size_t ws_size,
                              hipStream_t stream) {
    const int B = in_sizes[0] / (NWIN * DIM);  // 4096 windows
    unsigned short* wqkvT = (unsigned short*)d_ws;                   //    98304 B
    unsigned short* projT = (unsigned short*)((char*)d_ws + 98304);  //    32768 B
    float*          BM    = (float*)((char*)d_ws + 131072);          //  2458624 B

    prep_kernel<<<2657, 256, 0, stream>>>(
        (const float*)d_in[2],  // qkv_w
        (const float*)d_in[4],  // proj_w
        (const float*)d_in[1],  // mask
        (const float*)d_in[6],  // rel_bias_table
        (const int*)d_in[7],    // rel_index
        wqkvT, projT, BM);

    winattn_kernel<<<B, 512, 0, stream>>>(
        (const float*)d_in[0],  // x
        (const float*)d_in[3],  // qkv_b
        (const float*)d_in[5],  // proj_b
        wqkvT, projT, BM,
        (float*)d_out);
}